// Round 10
// baseline (1296.851 us; speedup 1.0000x reference)
//
#include <hip/hip_runtime.h>

// ---------------- problem constants ----------------
#define BQ   8
#define SQ   1569
#define BS   12552      // BQ*SQ
#define DM   768
#define NH   12
#define DH   64
#define TT   8
#define PP   196
#define D4   3072
#define QKVN 2304
#define MB_PAD 104      // 99 m-blocks padded to multiple of 8 for XCD-stable swizzle

typedef _Float16 f16;
typedef _Float16 f16x8 __attribute__((ext_vector_type(8)));
typedef float    f32x4 __attribute__((ext_vector_type(4)));
typedef unsigned long long u64;

#define AS1 __attribute__((address_space(1)))
#define AS3 __attribute__((address_space(3)))

#define Y_OFF    0ULL
#define QKV_OFF  19279872ULL
#define CTX_OFF  77119488ULL
#define H_OFF    19279872ULL
#define W_OFF    96399360ULL

// ROUND-8 LESSON (permanent): __threadfence() on gfx950 = agent-scope fence =
// L2 writeback/invalidate (per-XCD L2s non-coherent). Fine-grained cross-block
// fencing flushed L2 thousands of times per dispatch (attnA 65us -> 361us).
// Keep cross-block dependencies as separate dispatches; zero device fences here.
// ROUND-9 CHANGE: CLS attention de-split-K'd — one block per (b,h) does the
// full 1569-key softmax inside the attnA/attnB dispatches (hidden under the
// 4704/768 sibling blocks), eliminating both cls_comb dispatches + clsP buffer.

// ---------------- LayerNorm (wave per row) ----------------
__global__ __launch_bounds__(256) void ln_kernel(const float* __restrict__ x,
                                                 const float* __restrict__ g,
                                                 const float* __restrict__ bta,
                                                 f16* __restrict__ y) {
    int row = blockIdx.x * 4 + (threadIdx.x >> 6);
    int lane = threadIdx.x & 63;
    if (row >= BS) return;
    const float* xr = x + (u64)row * DM;
    float v[12];
    float s = 0.f, s2 = 0.f;
#pragma unroll
    for (int i = 0; i < 12; i++) { v[i] = xr[lane + i * 64]; s += v[i]; s2 += v[i] * v[i]; }
#pragma unroll
    for (int m = 1; m < 64; m <<= 1) { s += __shfl_xor(s, m, 64); s2 += __shfl_xor(s2, m, 64); }
    float mean = s * (1.f / 768.f);
    float var  = s2 * (1.f / 768.f) - mean * mean;
    float rstd = rsqrtf(var + 1e-12f);
    f16* yr = y + (u64)row * DM;
#pragma unroll
    for (int i = 0; i < 12; i++) {
        int c = lane + i * 64;
        yr[c] = (f16)((v[i] - mean) * rstd * g[c] + bta[c]);
    }
}

// ---------------- merged prep: 10 transposes + 2 bias concats + ln1 ----------------
__global__ __launch_bounds__(256) void prep_kernel(const float* __restrict__ t_Wq,
                                                   const float* __restrict__ t_Wk,
                                                   const float* __restrict__ t_Wv,
                                                   const float* __restrict__ t_Wo,
                                                   const float* __restrict__ s_Wq,
                                                   const float* __restrict__ s_Wk,
                                                   const float* __restrict__ s_Wv,
                                                   const float* __restrict__ s_Wo,
                                                   const float* __restrict__ W1,
                                                   const float* __restrict__ W2,
                                                   const float* __restrict__ t_bq,
                                                   const float* __restrict__ t_bk,
                                                   const float* __restrict__ t_bv,
                                                   const float* __restrict__ s_bq,
                                                   const float* __restrict__ s_bk,
                                                   const float* __restrict__ s_bv,
                                                   const float* __restrict__ x_in,
                                                   const float* __restrict__ ln1g,
                                                   const float* __restrict__ ln1b,
                                                   f16* __restrict__ y,
                                                   f16* __restrict__ tQKV,
                                                   f16* __restrict__ tWoT,
                                                   f16* __restrict__ sQKV,
                                                   f16* __restrict__ sWoT,
                                                   f16* __restrict__ W1T,
                                                   f16* __restrict__ W2T,
                                                   float* __restrict__ tBias,
                                                   float* __restrict__ sBias) {
    int id = blockIdx.x;
    int tid = threadIdx.x;

    if (id >= 9222) {                      // ---- ln1 ----
        int row = (id - 9222) * 4 + (tid >> 6);
        int lane = tid & 63;
        if (row >= BS) return;
        const float* xr = x_in + (u64)row * DM;
        float v[12];
        float s = 0.f, s2 = 0.f;
#pragma unroll
        for (int i = 0; i < 12; i++) { v[i] = xr[lane + i * 64]; s += v[i]; s2 += v[i] * v[i]; }
#pragma unroll
        for (int m = 1; m < 64; m <<= 1) { s += __shfl_xor(s, m, 64); s2 += __shfl_xor(s2, m, 64); }
        float mean = s * (1.f / 768.f);
        float var  = s2 * (1.f / 768.f) - mean * mean;
        float rstd = rsqrtf(var + 1e-12f);
        f16* yr = y + (u64)row * DM;
#pragma unroll
        for (int i = 0; i < 12; i++) {
            int c = lane + i * 64;
            yr[c] = (f16)((v[i] - mean) * rstd * ln1g[c] + ln1b[c]);
        }
        return;
    }

    if (id >= 9216) {                      // ---- bias concats ----
        int j = id - 9216;
        const float* a; const float* b; const float* c; float* dst;
        if (j < 3) { a = t_bq; b = t_bk; c = t_bv; dst = tBias; }
        else       { a = s_bq; b = s_bk; c = s_bv; dst = sBias; j -= 3; }
        int i = j * 256 + tid;
        if (i < 768) { dst[i] = a[i]; dst[i + 768] = b[i]; dst[i + 1536] = c[i]; }
        return;
    }

    const float* src; f16* dst; int R, C, bx, by;
    if (id < 4608) {
        int w = id / 576, t = id % 576;
        switch (w) {
            case 0: src = t_Wq; dst = tQKV;                break;
            case 1: src = t_Wk; dst = tQKV + 768 * 768;    break;
            case 2: src = t_Wv; dst = tQKV + 2 * 768 * 768; break;
            case 3: src = t_Wo; dst = tWoT;                break;
            case 4: src = s_Wq; dst = sQKV;                break;
            case 5: src = s_Wk; dst = sQKV + 768 * 768;    break;
            case 6: src = s_Wv; dst = sQKV + 2 * 768 * 768; break;
            default: src = s_Wo; dst = sWoT;               break;
        }
        R = 768; C = 768;
        bx = (t % 24) * 32; by = (t / 24) * 32;
    } else if (id < 6912) {
        int t = id - 4608;
        src = W1; dst = W1T; R = 768; C = 3072;
        bx = (t % 96) * 32; by = (t / 96) * 32;
    } else {
        int t = id - 6912;
        src = W2; dst = W2T; R = 3072; C = 768;
        bx = (t % 24) * 32; by = (t / 24) * 32;
    }

    __shared__ float tile[32][33];
    int tx = tid & 31, ty = tid >> 5;
#pragma unroll
    for (int i = 0; i < 4; i++) {
        int r = by + ty + i * 8, c = bx + tx;
        if (r < R && c < C) tile[ty + i * 8][tx] = src[(u64)r * C + c];
    }
    __syncthreads();
#pragma unroll
    for (int i = 0; i < 4; i++) {
        int c = bx + ty + i * 8, r = by + tx;
        if (c < C && r < R) dst[(u64)c * R + r] = (f16)tile[tx][ty + i * 8];
    }
}

// ---------------- GEMM v5 (verified config): R4 staging + 1-barrier dbuf ----------------
// Core loop locked (rounds 1-6: five structural variants all regressed;
// TLP at (256,4) is the mechanism).
template <int NOUT, bool GELU, bool RESID, bool OUTF16>
__global__ __launch_bounds__(256, 4) void gemm_kernel(const f16* __restrict__ A,
                                                      const f16* __restrict__ Bt,
                                                      const float* __restrict__ bias,
                                                      const float* __restrict__ resid,
                                                      float* __restrict__ Cf,
                                                      f16* __restrict__ Ch,
                                                      int K) {
    __shared__ __align__(16) f16 As[2][128 * 32];
    __shared__ __align__(16) f16 Bs[2][128 * 32];
    int id = blockIdx.x;
    int mb = id % MB_PAD, nb = id / MB_PAD;
    if (mb >= 99) return;
    int tid  = threadIdx.x;
    int lane = tid & 63, wave = tid >> 6;
    int wm = wave >> 1, wn = wave & 1;
    int m0 = mb * 128, n0 = nb * 128;
    int l15 = lane & 15, quad = lane >> 4;

    int r0   = wave * 16 + (lane >> 2);
    int coff = (lane & 3) * 8;
    const f16* ag0 = A + (u64)(m0 + r0) * K + coff;
    const f16* ag1 = A + (u64)(m0 + r0 + 64) * K + coff;
    bool av0 = (m0 + r0) < BS, av1 = (m0 + r0 + 64) < BS;
    const f16* bg0 = Bt + (u64)(n0 + r0) * K + coff;
    const f16* bg1 = Bt + (u64)(n0 + r0 + 64) * K + coff;
    int lofs = wave * 1024;

    f32x4 acc[4][4];
#pragma unroll
    for (int i = 0; i < 4; i++)
#pragma unroll
        for (int j = 0; j < 4; j++)
#pragma unroll
            for (int r = 0; r < 4; r++) acc[i][j][r] = 0.f;

    if (av0) __builtin_amdgcn_global_load_lds((const AS1 void*)ag0, (AS3 void*)((AS3 char*)&As[0][0] + lofs), 16, 0, 0);
    if (av1) __builtin_amdgcn_global_load_lds((const AS1 void*)ag1, (AS3 void*)((AS3 char*)&As[0][0] + lofs + 4096), 16, 0, 0);
    __builtin_amdgcn_global_load_lds((const AS1 void*)bg0, (AS3 void*)((AS3 char*)&Bs[0][0] + lofs), 16, 0, 0);
    __builtin_amdgcn_global_load_lds((const AS1 void*)bg1, (AS3 void*)((AS3 char*)&Bs[0][0] + lofs + 4096), 16, 0, 0);
    ag0 += 32; ag1 += 32; bg0 += 32; bg1 += 32;

    int nit = K >> 5;
    for (int it = 0; it < nit; it++) {
        __syncthreads();
        int buf = it & 1;
        if (it + 1 < nit) {
            int nb2 = buf ^ 1;
            if (av0) __builtin_amdgcn_global_load_lds((const AS1 void*)ag0, (AS3 void*)((AS3 char*)&As[nb2][0] + lofs), 16, 0, 0);
            if (av1) __builtin_amdgcn_global_load_lds((const AS1 void*)ag1, (AS3 void*)((AS3 char*)&As[nb2][0] + lofs + 4096), 16, 0, 0);
            __builtin_amdgcn_global_load_lds((const AS1 void*)bg0, (AS3 void*)((AS3 char*)&Bs[nb2][0] + lofs), 16, 0, 0);
            __builtin_amdgcn_global_load_lds((const AS1 void*)bg1, (AS3 void*)((AS3 char*)&Bs[nb2][0] + lofs + 4096), 16, 0, 0);
            ag0 += 32; ag1 += 32; bg0 += 32; bg1 += 32;
        }
        f16x8 af[4], bf[4];
#pragma unroll
        for (int i = 0; i < 4; i++)
            af[i] = *(const f16x8*)(&As[buf][(wm * 64 + i * 16 + l15) * 32 + quad * 8]);
#pragma unroll
        for (int j = 0; j < 4; j++)
            bf[j] = *(const f16x8*)(&Bs[buf][(wn * 64 + j * 16 + l15) * 32 + quad * 8]);
#pragma unroll
        for (int i = 0; i < 4; i++)
#pragma unroll
            for (int j = 0; j < 4; j++)
                acc[i][j] = __builtin_amdgcn_mfma_f32_16x16x32_f16(af[i], bf[j], acc[i][j], 0, 0, 0);
    }

#pragma unroll
    for (int i = 0; i < 4; i++) {
#pragma unroll
        for (int j = 0; j < 4; j++) {
            int col = n0 + wn * 64 + j * 16 + l15;
            float bv = bias[col];
#pragma unroll
            for (int r = 0; r < 4; r++) {
                int row = m0 + wm * 64 + i * 16 + quad * 4 + r;
                if (row < BS) {
                    float v = acc[i][j][r] + bv;
                    if (GELU) {
                        // tanh-approx GELU (max dev ~3e-3 from exact erf form)
                        float u = 0.7978845608028654f * (v + 0.044715f * v * v * v);
                        float e = __builtin_exp2f(-2.885390081777927f * u);
                        v = v / (1.f + e);
                    }
                    if (RESID) v += resid[(u64)row * NOUT + col];
                    if (OUTF16) Ch[(u64)row * NOUT + col] = (f16)v;
                    else        Cf[(u64)row * NOUT + col] = v;
                }
            }
        }
    }
}

// ---------------- CLS full attention: one block per (b,h), all 1569 keys ----------------
// Two-pass over an LDS score buffer; writes ctx CLS row directly. No split-K,
// no combine dispatch, no fences. Runs inside attnA/attnB dispatches where the
// sibling blocks dominate the makespan (these 96 blocks hide under them).
__device__ __forceinline__ void cls_full_body(const f16* __restrict__ qkv,
                                              f16* __restrict__ ctx,
                                              int bh,
                                              float* sc, float* accbuf, float* lbuf,
                                              float* mxs) {
    int b = bh / NH, h = bh % NH;
    u64 bb = (u64)b * SQ;
    int tid = threadIdx.x, lane = tid & 63, wave = tid >> 6;
    float qd = (float)qkv[bb * QKVN + h * 64 + lane];
    // pass 1: scores
    for (int jj = wave; jj < SQ; jj += 4) {
        float p = qd * (float)qkv[(bb + jj) * QKVN + 768 + h * 64 + lane];
#pragma unroll
        for (int m = 1; m < 64; m <<= 1) p += __shfl_xor(p, m, 64);
        if (lane == 0) sc[jj] = p * 0.125f;
    }
    __syncthreads();
    // block max
    if (wave == 0) {
        float m = -1e30f;
        for (int j = lane; j < SQ; j += 64) m = fmaxf(m, sc[j]);
#pragma unroll
        for (int s = 1; s < 64; s <<= 1) m = fmaxf(m, __shfl_xor(m, s, 64));
        if (lane == 0) *mxs = m;
    }
    __syncthreads();
    float mx = *mxs;
    // pass 2: exp-sum + weighted V
    float acc = 0.f, l = 0.f;
    for (int jj = wave; jj < SQ; jj += 4) {
        float w = expf(sc[jj] - mx);
        l += w;
        acc += w * (float)qkv[(bb + jj) * QKVN + 1536 + h * 64 + lane];
    }
    accbuf[wave * 64 + lane] = acc;
    if (lane == 0) lbuf[wave] = l;
    __syncthreads();
    if (tid < 64) {
        float a = accbuf[tid] + accbuf[64 + tid] + accbuf[128 + tid] + accbuf[192 + tid];
        float lt = lbuf[0] + lbuf[1] + lbuf[2] + lbuf[3];
        ctx[(bb) * DM + h * 64 + lane] = (f16)(a / lt);
    }
}

// ---------------- phase-A attention: time_attn [0,4704) + cls_full [4704,4800) ----------------
__global__ __launch_bounds__(256) void attnA_kernel(const f16* __restrict__ qkv,
                                                    f16* __restrict__ ctx) {
    __shared__ float sc[SQ];          // 6276 B (allocated for all blocks; fine)
    __shared__ float accbuf[4 * 64];
    __shared__ float lbuf[4];
    __shared__ float mxs;
    int tid = threadIdx.x, lane = tid & 63, wave = tid >> 6;
    if (blockIdx.x >= 4704) {
        cls_full_body(qkv, ctx, blockIdx.x - 4704, sc, accbuf, lbuf, &mxs);
        return;
    }
    int w = blockIdx.x * 4 + wave;
    int b = w / (NH * PP);
    int rem = w % (NH * PP);
    int h = rem / PP, p = rem % PP;
    u64 bb = (u64)b * SQ;
    int hoff = h * 64 + lane;

    float qv[TT], kv[9], vv[9];
#pragma unroll
    for (int t = 0; t < TT; t++) qv[t] = (float)qkv[(bb + 1 + t * PP + p) * QKVN + hoff];
    kv[0] = (float)qkv[bb * QKVN + 768 + hoff];
    vv[0] = (float)qkv[bb * QKVN + 1536 + hoff];
#pragma unroll
    for (int j = 1; j <= TT; j++) {
        u64 ro = (bb + 1 + (u64)(j - 1) * PP + p) * QKVN;
        kv[j] = (float)qkv[ro + 768 + hoff];
        vv[j] = (float)qkv[ro + 1536 + hoff];
    }
#pragma unroll
    for (int t = 0; t < TT; t++) {
        float s[9];
#pragma unroll
        for (int j = 0; j < 9; j++) {
            float ps = qv[t] * kv[j];
#pragma unroll
            for (int m = 1; m < 64; m <<= 1) ps += __shfl_xor(ps, m, 64);
            s[j] = ps * 0.125f;
        }
        float mx = s[0];
#pragma unroll
        for (int j = 1; j < 9; j++) mx = fmaxf(mx, s[j]);
        float sum = 0.f;
#pragma unroll
        for (int j = 0; j < 9; j++) { s[j] = expf(s[j] - mx); sum += s[j]; }
        float o = 0.f;
#pragma unroll
        for (int j = 0; j < 9; j++) o += s[j] * vv[j];
        o /= sum;
        ctx[(bb + 1 + (u64)t * PP + p) * DM + h * 64 + lane] = (f16)o;
    }
}

// ---------------- phase-B attention: space_attn [0,768) + cls_full [768,864) ----------------
// Shared-union keeps LDS at the space kernel's 59KB for all blocks.
__global__ __launch_bounds__(256) void attnB_kernel(const f16* __restrict__ qkv,
                                                    f16* __restrict__ ctx) {
    __shared__ __align__(16) char smem[64 * 232 * 2 + 4 * 16 * 232 * 2];
    int tid = threadIdx.x, lane = tid & 63, wave = tid >> 6;
    if (blockIdx.x >= 768) {
        float* sc     = (float*)smem;                     // 6276 B
        float* accbuf = (float*)(smem + 6400);            // 1 KB
        float* lbuf   = (float*)(smem + 7424);            // 16 B
        float* mxs    = (float*)(smem + 7440);
        cls_full_body(qkv, ctx, blockIdx.x - 768, sc, accbuf, lbuf, mxs);
        return;
    }
    f16* Vt = (f16*)smem;
    f16* Ps = (f16*)(smem + 64 * 232 * 2);
    int g = blockIdx.x;
    int b = g / (NH * TT);
    int rem = g % (NH * TT);
    int h = rem / TT, t = rem % TT;
    u64 bb = (u64)b * SQ;
    int l15 = lane & 15, quad = lane >> 4;

    for (int i = tid; i < 4 * 16 * 232 * 2 / 16; i += 256)
        ((uint4*)Ps)[i] = make_uint4(0u, 0u, 0u, 0u);

    for (int idx = tid; idx < 232 * 8; idx += 256) {
        int c8 = idx / 232;
        int j  = idx - c8 * 232;
        int c  = c8 * 8;
        uint4 vraw = make_uint4(0u, 0u, 0u, 0u);
        if (j < 197) {
            int tok = (j == 0) ? 0 : (1 + t * PP + (j - 1));
            vraw = *(const uint4*)(qkv + (bb + tok) * QKVN + 1536 + h * 64 + c);
        }
        f16x8 vv = *(f16x8*)&vraw;
#pragma unroll
        for (int e = 0; e < 8; e++) Vt[(c + e) * 232 + j] = vv[e];
    }
    __syncthreads();

    f16* myP = Ps + wave * 16 * 232;
    for (int qt = wave; qt < 13; qt += 4) {
        int mloc = qt * 16 + l15;
        int mc = mloc > 195 ? 195 : mloc;
        const f16* qr = qkv + (bb + 1 + (u64)t * PP + mc) * QKVN + h * 64;
        f16x8 qa0 = *(const f16x8*)(qr + quad * 8);
        f16x8 qa1 = *(const f16x8*)(qr + 32 + quad * 8);

        f32x4 s[13];
#pragma unroll
        for (int nt = 0; nt < 13; nt++) { s[nt][0] = 0.f; s[nt][1] = 0.f; s[nt][2] = 0.f; s[nt][3] = 0.f; }
#pragma unroll
        for (int nt = 0; nt < 13; nt++) {
            int n = nt * 16 + l15;
            int ncl = n > 196 ? 196 : n;
            int tok = (ncl == 0) ? 0 : (1 + t * PP + (ncl - 1));
            const f16* kr = qkv + (bb + tok) * QKVN + 768 + h * 64;
            f16x8 kb0 = *(const f16x8*)(kr + quad * 8);
            f16x8 kb1 = *(const f16x8*)(kr + 32 + quad * 8);
            s[nt] = __builtin_amdgcn_mfma_f32_16x16x32_f16(qa0, kb0, s[nt], 0, 0, 0);
            s[nt] = __builtin_amdgcn_mfma_f32_16x16x32_f16(qa1, kb1, s[nt], 0, 0, 0);
        }
        if (l15 >= 5) { s[12][0] = -1e30f; s[12][1] = -1e30f; s[12][2] = -1e30f; s[12][3] = -1e30f; }

        float mx[4] = {-1e30f, -1e30f, -1e30f, -1e30f};
#pragma unroll
        for (int nt = 0; nt < 13; nt++)
#pragma unroll
            for (int r = 0; r < 4; r++) mx[r] = fmaxf(mx[r], s[nt][r]);
#pragma unroll
        for (int m = 1; m < 16; m <<= 1)
#pragma unroll
            for (int r = 0; r < 4; r++) mx[r] = fmaxf(mx[r], __shfl_xor(mx[r], m, 64));

        float sum[4] = {0.f, 0.f, 0.f, 0.f};
#pragma unroll
        for (int nt = 0; nt < 13; nt++)
#pragma unroll
            for (int r = 0; r < 4; r++) {
                float p = exp2f((s[nt][r] - mx[r]) * 0.18033688011112042f);
                s[nt][r] = p;
                sum[r] += p;
            }
#pragma unroll
        for (int m = 1; m < 16; m <<= 1)
#pragma unroll
            for (int r = 0; r < 4; r++) sum[r] += __shfl_xor(sum[r], m, 64);

#pragma unroll
        for (int nt = 0; nt < 13; nt++)
#pragma unroll
            for (int r = 0; r < 4; r++)
                myP[(quad * 4 + r) * 232 + nt * 16 + l15] = (f16)s[nt][r];

        f32x4 o[4];
#pragma unroll
        for (int n2 = 0; n2 < 4; n2++) { o[n2][0] = 0.f; o[n2][1] = 0.f; o[n2][2] = 0.f; o[n2][3] = 0.f; }
#pragma unroll
        for (int kc = 0; kc < 7; kc++) {
            f16x8 pa = *(const f16x8*)(&myP[l15 * 232 + kc * 32 + quad * 8]);
#pragma unroll
            for (int n2 = 0; n2 < 4; n2++) {
                f16x8 vb = *(const f16x8*)(&Vt[(n2 * 16 + l15) * 232 + kc * 32 + quad * 8]);
                o[n2] = __builtin_amdgcn_mfma_f32_16x16x32_f16(pa, vb, o[n2], 0, 0, 0);
            }
        }

        float inv[4];
#pragma unroll
        for (int r = 0; r < 4; r++) inv[r] = 1.f / sum[r];
#pragma unroll
        for (int n2 = 0; n2 < 4; n2++)
#pragma unroll
            for (int r = 0; r < 4; r++) {
                int m = qt * 16 + quad * 4 + r;
                if (m < PP)
                    ctx[(bb + 1 + (u64)t * PP + m) * DM + h * 64 + n2 * 16 + l15] = (f16)(o[n2][r] * inv[r]);
            }
    }
}

// ---------------- host: 11 dispatches, fence-free ----------------
extern "C" void kernel_launch(void* const* d_in, const int* in_sizes, int n_in,
                              void* d_out, int out_size, void* d_ws, size_t ws_size,
                              hipStream_t stream) {
    const float* x_in  = (const float*)d_in[0];
    const float* t_Wq  = (const float*)d_in[1];
    const float* t_bq  = (const float*)d_in[2];
    const float* t_Wk  = (const float*)d_in[3];
    const float* t_bk  = (const float*)d_in[4];
    const float* t_Wv  = (const float*)d_in[5];
    const float* t_bv  = (const float*)d_in[6];
    const float* t_Wo  = (const float*)d_in[7];
    const float* t_bo  = (const float*)d_in[8];
    const float* s_Wq  = (const float*)d_in[9];
    const float* s_bq  = (const float*)d_in[10];
    const float* s_Wk  = (const float*)d_in[11];
    const float* s_bk  = (const float*)d_in[12];
    const float* s_Wv  = (const float*)d_in[13];
    const float* s_bv  = (const float*)d_in[14];
    const float* s_Wo  = (const float*)d_in[15];
    const float* s_bo  = (const float*)d_in[16];
    const float* W1    = (const float*)d_in[17];
    const float* b1    = (const float*)d_in[18];
    const float* W2    = (const float*)d_in[19];
    const float* b2    = (const float*)d_in[20];
    const float* ln1g  = (const float*)d_in[21];
    const float* ln1b  = (const float*)d_in[22];
    const float* ln2g  = (const float*)d_in[23];
    const float* ln2b  = (const float*)d_in[24];
    const float* ln3g  = (const float*)d_in[25];
    const float* ln3b  = (const float*)d_in[26];

    char* ws = (char*)d_ws;
    f16* y    = (f16*)(ws + Y_OFF);
    f16* qkv  = (f16*)(ws + QKV_OFF);
    f16* ctx  = (f16*)(ws + CTX_OFF);
    f16* hbuf = (f16*)(ws + H_OFF);
    char* wreg = ws + W_OFF;
    f16* tQKV  = (f16*)(wreg);
    f16* tWoT  = (f16*)(wreg + 3538944);
    f16* sQKV  = (f16*)(wreg + 4718592);
    f16* sWoT  = (f16*)(wreg + 8257536);
    f16* W1T   = (f16*)(wreg + 9437184);
    f16* W2T   = (f16*)(wreg + 14155776);
    float* tBias = (float*)(wreg + 18874368);
    float* sBias = (float*)(wreg + 18883584);
    float* xcur  = (float*)d_out;

    dim3 tb(256);
    // 1: weight prep + ln1
    prep_kernel<<<12360, tb, 0, stream>>>(t_Wq, t_Wk, t_Wv, t_Wo, s_Wq, s_Wk, s_Wv, s_Wo,
                                          W1, W2, t_bq, t_bk, t_bv, s_bq, s_bk, s_bv,
                                          x_in, ln1g, ln1b, y,
                                          tQKV, tWoT, sQKV, sWoT, W1T, W2T, tBias, sBias);
    // 2: QKV (time)
    gemm_kernel<QKVN, false, false, true><<<MB_PAD * 18, tb, 0, stream>>>(y, tQKV, tBias, nullptr, nullptr, qkv, 768);
    // 3: time attn + CLS full attention
    attnA_kernel<<<4800, tb, 0, stream>>>(qkv, ctx);
    // 4: Wo (time) + resid
    gemm_kernel<DM, false, true, false><<<MB_PAD * 6, tb, 0, stream>>>(ctx, tWoT, t_bo, x_in, xcur, nullptr, 768);
    // 5: ln2
    ln_kernel<<<3138, tb, 0, stream>>>(xcur, ln2g, ln2b, y);
    // 6: QKV (space)
    gemm_kernel<QKVN, false, false, true><<<MB_PAD * 18, tb, 0, stream>>>(y, sQKV, sBias, nullptr, nullptr, qkv, 768);
    // 7: space attn + CLS full attention
    attnB_kernel<<<864, tb, 0, stream>>>(qkv, ctx);
    // 8: Wo (space) + resid
    gemm_kernel<DM, false, true, false><<<MB_PAD * 6, tb, 0, stream>>>(ctx, sWoT, s_bo, xcur, xcur, nullptr, 768);
    // 9: ln3
    ln_kernel<<<3138, tb, 0, stream>>>(xcur, ln3g, ln3b, y);
    // 10: FFN1 + gelu
    gemm_kernel<D4, true, false, true><<<MB_PAD * 24, tb, 0, stream>>>(y, W1T, b1, nullptr, nullptr, hbuf, 768);
    // 11: FFN2 + resid (final output)
    gemm_kernel<DM, false, true, false><<<MB_PAD * 6, tb, 0, stream>>>(hbuf, W2T, b2, xcur, xcur, nullptr, 3072);
}

// Round 11
// 842.693 us; speedup vs baseline: 1.5389x; 1.5389x over previous
//
#include <hip/hip_runtime.h>

// ---------------- problem constants ----------------
#define BQ   8
#define SQ   1569
#define BS   12552      // BQ*SQ
#define DM   768
#define NH   12
#define DH   64
#define TT   8
#define PP   196
#define D4   3072
#define QKVN 2304
#define CCH  24         // CLS split-K chunks
#define CKEY 66         // keys per chunk (24*66 = 1584 >= 1569)
#define MB_PAD 104      // 99 m-blocks padded to multiple of 8 for XCD-stable swizzle

typedef _Float16 f16;
typedef _Float16 f16x8 __attribute__((ext_vector_type(8)));
typedef float    f32x4 __attribute__((ext_vector_type(4)));
typedef unsigned long long u64;

#define AS1 __attribute__((address_space(1)))
#define AS3 __attribute__((address_space(3)))

#define Y_OFF    0ULL
#define QKV_OFF  19279872ULL
#define CTX_OFF  77119488ULL
#define H_OFF    19279872ULL
#define W_OFF    96399360ULL

// ROUND-8 LESSON (permanent): __threadfence() on gfx950 = agent-scope fence =
// L2 writeback/invalidate (per-XCD L2s non-coherent). Fine-grained cross-block
// fencing flushed L2 thousands of times per dispatch (attnA 65us -> 361us).
// ROUND-10 LESSON (permanent): merging work into a dispatch only helps if its
// critical path <= the host dispatch's makespan. De-split-K'ing CLS (96 blocks
// x 1569 serial keys) left a 300us single-block tail at 0.4 blocks/CU ->
// attnA 65us -> 374us. CLS stays split-K (24-way) + separate 24-block combine.

// ---------------- LayerNorm (wave per row) ----------------
__global__ __launch_bounds__(256) void ln_kernel(const float* __restrict__ x,
                                                 const float* __restrict__ g,
                                                 const float* __restrict__ bta,
                                                 f16* __restrict__ y) {
    int row = blockIdx.x * 4 + (threadIdx.x >> 6);
    int lane = threadIdx.x & 63;
    if (row >= BS) return;
    const float* xr = x + (u64)row * DM;
    float v[12];
    float s = 0.f, s2 = 0.f;
#pragma unroll
    for (int i = 0; i < 12; i++) { v[i] = xr[lane + i * 64]; s += v[i]; s2 += v[i] * v[i]; }
#pragma unroll
    for (int m = 1; m < 64; m <<= 1) { s += __shfl_xor(s, m, 64); s2 += __shfl_xor(s2, m, 64); }
    float mean = s * (1.f / 768.f);
    float var  = s2 * (1.f / 768.f) - mean * mean;
    float rstd = rsqrtf(var + 1e-12f);
    f16* yr = y + (u64)row * DM;
#pragma unroll
    for (int i = 0; i < 12; i++) {
        int c = lane + i * 64;
        yr[c] = (f16)((v[i] - mean) * rstd * g[c] + bta[c]);
    }
}

// ---------------- merged prep: 10 transposes + 2 bias concats + ln1 (fence-free) ----------------
__global__ __launch_bounds__(256) void prep_kernel(const float* __restrict__ t_Wq,
                                                   const float* __restrict__ t_Wk,
                                                   const float* __restrict__ t_Wv,
                                                   const float* __restrict__ t_Wo,
                                                   const float* __restrict__ s_Wq,
                                                   const float* __restrict__ s_Wk,
                                                   const float* __restrict__ s_Wv,
                                                   const float* __restrict__ s_Wo,
                                                   const float* __restrict__ W1,
                                                   const float* __restrict__ W2,
                                                   const float* __restrict__ t_bq,
                                                   const float* __restrict__ t_bk,
                                                   const float* __restrict__ t_bv,
                                                   const float* __restrict__ s_bq,
                                                   const float* __restrict__ s_bk,
                                                   const float* __restrict__ s_bv,
                                                   const float* __restrict__ x_in,
                                                   const float* __restrict__ ln1g,
                                                   const float* __restrict__ ln1b,
                                                   f16* __restrict__ y,
                                                   f16* __restrict__ tQKV,
                                                   f16* __restrict__ tWoT,
                                                   f16* __restrict__ sQKV,
                                                   f16* __restrict__ sWoT,
                                                   f16* __restrict__ W1T,
                                                   f16* __restrict__ W2T,
                                                   float* __restrict__ tBias,
                                                   float* __restrict__ sBias) {
    int id = blockIdx.x;
    int tid = threadIdx.x;

    if (id >= 9222) {                      // ---- ln1 ----
        int row = (id - 9222) * 4 + (tid >> 6);
        int lane = tid & 63;
        if (row >= BS) return;
        const float* xr = x_in + (u64)row * DM;
        float v[12];
        float s = 0.f, s2 = 0.f;
#pragma unroll
        for (int i = 0; i < 12; i++) { v[i] = xr[lane + i * 64]; s += v[i]; s2 += v[i] * v[i]; }
#pragma unroll
        for (int m = 1; m < 64; m <<= 1) { s += __shfl_xor(s, m, 64); s2 += __shfl_xor(s2, m, 64); }
        float mean = s * (1.f / 768.f);
        float var  = s2 * (1.f / 768.f) - mean * mean;
        float rstd = rsqrtf(var + 1e-12f);
        f16* yr = y + (u64)row * DM;
#pragma unroll
        for (int i = 0; i < 12; i++) {
            int c = lane + i * 64;
            yr[c] = (f16)((v[i] - mean) * rstd * ln1g[c] + ln1b[c]);
        }
        return;
    }

    if (id >= 9216) {                      // ---- bias concats ----
        int j = id - 9216;
        const float* a; const float* b; const float* c; float* dst;
        if (j < 3) { a = t_bq; b = t_bk; c = t_bv; dst = tBias; }
        else       { a = s_bq; b = s_bk; c = s_bv; dst = sBias; j -= 3; }
        int i = j * 256 + tid;
        if (i < 768) { dst[i] = a[i]; dst[i + 768] = b[i]; dst[i + 1536] = c[i]; }
        return;
    }

    const float* src; f16* dst; int R, C, bx, by;
    if (id < 4608) {
        int w = id / 576, t = id % 576;
        switch (w) {
            case 0: src = t_Wq; dst = tQKV;                break;
            case 1: src = t_Wk; dst = tQKV + 768 * 768;    break;
            case 2: src = t_Wv; dst = tQKV + 2 * 768 * 768; break;
            case 3: src = t_Wo; dst = tWoT;                break;
            case 4: src = s_Wq; dst = sQKV;                break;
            case 5: src = s_Wk; dst = sQKV + 768 * 768;    break;
            case 6: src = s_Wv; dst = sQKV + 2 * 768 * 768; break;
            default: src = s_Wo; dst = sWoT;               break;
        }
        R = 768; C = 768;
        bx = (t % 24) * 32; by = (t / 24) * 32;
    } else if (id < 6912) {
        int t = id - 4608;
        src = W1; dst = W1T; R = 768; C = 3072;
        bx = (t % 96) * 32; by = (t / 96) * 32;
    } else {
        int t = id - 6912;
        src = W2; dst = W2T; R = 3072; C = 768;
        bx = (t % 24) * 32; by = (t / 24) * 32;
    }

    __shared__ float tile[32][33];
    int tx = tid & 31, ty = tid >> 5;
#pragma unroll
    for (int i = 0; i < 4; i++) {
        int r = by + ty + i * 8, c = bx + tx;
        if (r < R && c < C) tile[ty + i * 8][tx] = src[(u64)r * C + c];
    }
    __syncthreads();
#pragma unroll
    for (int i = 0; i < 4; i++) {
        int c = bx + ty + i * 8, r = by + tx;
        if (c < C && r < R) dst[(u64)c * R + r] = (f16)tile[tx][ty + i * 8];
    }
}

// ---------------- GEMM v5 (verified config): R4 staging + 1-barrier dbuf ----------------
// Core loop locked (rounds 1-6: five structural variants all regressed;
// TLP at (256,4) is the mechanism).
template <int NOUT, bool GELU, bool RESID, bool OUTF16>
__global__ __launch_bounds__(256, 4) void gemm_kernel(const f16* __restrict__ A,
                                                      const f16* __restrict__ Bt,
                                                      const float* __restrict__ bias,
                                                      const float* __restrict__ resid,
                                                      float* __restrict__ Cf,
                                                      f16* __restrict__ Ch,
                                                      int K) {
    __shared__ __align__(16) f16 As[2][128 * 32];
    __shared__ __align__(16) f16 Bs[2][128 * 32];
    int id = blockIdx.x;
    int mb = id % MB_PAD, nb = id / MB_PAD;
    if (mb >= 99) return;
    int tid  = threadIdx.x;
    int lane = tid & 63, wave = tid >> 6;
    int wm = wave >> 1, wn = wave & 1;
    int m0 = mb * 128, n0 = nb * 128;
    int l15 = lane & 15, quad = lane >> 4;

    int r0   = wave * 16 + (lane >> 2);
    int coff = (lane & 3) * 8;
    const f16* ag0 = A + (u64)(m0 + r0) * K + coff;
    const f16* ag1 = A + (u64)(m0 + r0 + 64) * K + coff;
    bool av0 = (m0 + r0) < BS, av1 = (m0 + r0 + 64) < BS;
    const f16* bg0 = Bt + (u64)(n0 + r0) * K + coff;
    const f16* bg1 = Bt + (u64)(n0 + r0 + 64) * K + coff;
    int lofs = wave * 1024;

    f32x4 acc[4][4];
#pragma unroll
    for (int i = 0; i < 4; i++)
#pragma unroll
        for (int j = 0; j < 4; j++)
#pragma unroll
            for (int r = 0; r < 4; r++) acc[i][j][r] = 0.f;

    if (av0) __builtin_amdgcn_global_load_lds((const AS1 void*)ag0, (AS3 void*)((AS3 char*)&As[0][0] + lofs), 16, 0, 0);
    if (av1) __builtin_amdgcn_global_load_lds((const AS1 void*)ag1, (AS3 void*)((AS3 char*)&As[0][0] + lofs + 4096), 16, 0, 0);
    __builtin_amdgcn_global_load_lds((const AS1 void*)bg0, (AS3 void*)((AS3 char*)&Bs[0][0] + lofs), 16, 0, 0);
    __builtin_amdgcn_global_load_lds((const AS1 void*)bg1, (AS3 void*)((AS3 char*)&Bs[0][0] + lofs + 4096), 16, 0, 0);
    ag0 += 32; ag1 += 32; bg0 += 32; bg1 += 32;

    int nit = K >> 5;
    for (int it = 0; it < nit; it++) {
        __syncthreads();
        int buf = it & 1;
        if (it + 1 < nit) {
            int nb2 = buf ^ 1;
            if (av0) __builtin_amdgcn_global_load_lds((const AS1 void*)ag0, (AS3 void*)((AS3 char*)&As[nb2][0] + lofs), 16, 0, 0);
            if (av1) __builtin_amdgcn_global_load_lds((const AS1 void*)ag1, (AS3 void*)((AS3 char*)&As[nb2][0] + lofs + 4096), 16, 0, 0);
            __builtin_amdgcn_global_load_lds((const AS1 void*)bg0, (AS3 void*)((AS3 char*)&Bs[nb2][0] + lofs), 16, 0, 0);
            __builtin_amdgcn_global_load_lds((const AS1 void*)bg1, (AS3 void*)((AS3 char*)&Bs[nb2][0] + lofs + 4096), 16, 0, 0);
            ag0 += 32; ag1 += 32; bg0 += 32; bg1 += 32;
        }
        f16x8 af[4], bf[4];
#pragma unroll
        for (int i = 0; i < 4; i++)
            af[i] = *(const f16x8*)(&As[buf][(wm * 64 + i * 16 + l15) * 32 + quad * 8]);
#pragma unroll
        for (int j = 0; j < 4; j++)
            bf[j] = *(const f16x8*)(&Bs[buf][(wn * 64 + j * 16 + l15) * 32 + quad * 8]);
#pragma unroll
        for (int i = 0; i < 4; i++)
#pragma unroll
            for (int j = 0; j < 4; j++)
                acc[i][j] = __builtin_amdgcn_mfma_f32_16x16x32_f16(af[i], bf[j], acc[i][j], 0, 0, 0);
    }

#pragma unroll
    for (int i = 0; i < 4; i++) {
#pragma unroll
        for (int j = 0; j < 4; j++) {
            int col = n0 + wn * 64 + j * 16 + l15;
            float bv = bias[col];
#pragma unroll
            for (int r = 0; r < 4; r++) {
                int row = m0 + wm * 64 + i * 16 + quad * 4 + r;
                if (row < BS) {
                    float v = acc[i][j][r] + bv;
                    if (GELU) {
                        // tanh-approx GELU (max dev ~3e-3 from exact erf form)
                        float u = 0.7978845608028654f * (v + 0.044715f * v * v * v);
                        float e = __builtin_exp2f(-2.885390081777927f * u);
                        v = v / (1.f + e);
                    }
                    if (RESID) v += resid[(u64)row * NOUT + col];
                    if (OUTF16) Ch[(u64)row * NOUT + col] = (f16)v;
                    else        Cf[(u64)row * NOUT + col] = v;
                }
            }
        }
    }
}

// ---------------- CLS split-K part body (NO fences/atomics; combine is separate dispatch) ----------------
__device__ __forceinline__ void cls_part_body(const f16* __restrict__ qkv,
                                              float* __restrict__ part,
                                              int g,
                                              float* sc, float* accbuf, float* lbuf,
                                              float* mxs) {
    int c = g % CCH, bh = g / CCH;
    int b = bh / NH, h = bh % NH;
    u64 bb = (u64)b * SQ;
    int tid = threadIdx.x, lane = tid & 63, wave = tid >> 6;
    float qd = (float)qkv[bb * QKVN + h * 64 + lane];
    int j0 = c * CKEY;
    int cnt = SQ - j0; if (cnt > CKEY) cnt = CKEY;
    for (int jj = wave; jj < cnt; jj += 4) {
        float p = qd * (float)qkv[(bb + j0 + jj) * QKVN + 768 + h * 64 + lane];
#pragma unroll
        for (int m = 1; m < 64; m <<= 1) p += __shfl_xor(p, m, 64);
        if (lane == 0) sc[jj] = p * 0.125f;
    }
    __syncthreads();
    if (wave == 0) {
        float m = -1e30f;
        for (int j = lane; j < cnt; j += 64) m = fmaxf(m, sc[j]);
#pragma unroll
        for (int s = 1; s < 64; s <<= 1) m = fmaxf(m, __shfl_xor(m, s, 64));
        if (lane == 0) *mxs = m;
    }
    __syncthreads();
    float mx = *mxs;
    float acc = 0.f, l = 0.f;
    for (int jj = wave; jj < cnt; jj += 4) {
        float w = expf(sc[jj] - mx);
        l += w;
        acc += w * (float)qkv[(bb + j0 + jj) * QKVN + 1536 + h * 64 + lane];
    }
    accbuf[wave * 64 + lane] = acc;
    if (lane == 0) lbuf[wave] = l;
    __syncthreads();
    if (tid < 64) {
        float a = accbuf[tid] + accbuf[64 + tid] + accbuf[128 + tid] + accbuf[192 + tid];
        float* pb = part + ((u64)bh * CCH + c) * 66;
        if (tid == 0) { pb[0] = *mxs; pb[1] = lbuf[0] + lbuf[1] + lbuf[2] + lbuf[3]; }
        pb[2 + tid] = a;
    }
}

// ---------------- CLS attention split-K: combine kernel, wave per (b,h) ----------------
__global__ __launch_bounds__(256) void cls_comb_kernel(const float* __restrict__ part,
                                                       f16* __restrict__ ctx) {
    int w = blockIdx.x * 4 + (threadIdx.x >> 6);
    int lane = threadIdx.x & 63;
    if (w >= BQ * NH) return;
    int b = w / NH, h = w % NH;
    const float* pb = part + (u64)w * CCH * 66;
    float m = (lane < CCH) ? pb[lane * 66] : -1e30f;
#pragma unroll
    for (int s = 1; s < 64; s <<= 1) m = fmaxf(m, __shfl_xor(m, s, 64));
    float l = (lane < CCH) ? pb[lane * 66 + 1] * expf(pb[lane * 66] - m) : 0.f;
#pragma unroll
    for (int s = 1; s < 64; s <<= 1) l += __shfl_xor(l, s, 64);
    float o = 0.f;
    for (int j = 0; j < CCH; j++) {
        float mj = pb[j * 66];
        o += pb[j * 66 + 2 + lane] * expf(mj - m);
    }
    ctx[((u64)b * SQ) * DM + h * 64 + lane] = (f16)(o / l);
}

// ---------------- phase-A attention: time_attn [0,4704) + cls_part [4704,7008) ----------------
__global__ __launch_bounds__(256) void attnA_kernel(const f16* __restrict__ qkv,
                                                    f16* __restrict__ ctx,
                                                    float* __restrict__ part) {
    int tid = threadIdx.x, lane = tid & 63, wave = tid >> 6;
    if (blockIdx.x < 4704) {
        int w = blockIdx.x * 4 + wave;
        int b = w / (NH * PP);
        int rem = w % (NH * PP);
        int h = rem / PP, p = rem % PP;
        u64 bb = (u64)b * SQ;
        int hoff = h * 64 + lane;

        float qv[TT], kv[9], vv[9];
#pragma unroll
        for (int t = 0; t < TT; t++) qv[t] = (float)qkv[(bb + 1 + t * PP + p) * QKVN + hoff];
        kv[0] = (float)qkv[bb * QKVN + 768 + hoff];
        vv[0] = (float)qkv[bb * QKVN + 1536 + hoff];
#pragma unroll
        for (int j = 1; j <= TT; j++) {
            u64 ro = (bb + 1 + (u64)(j - 1) * PP + p) * QKVN;
            kv[j] = (float)qkv[ro + 768 + hoff];
            vv[j] = (float)qkv[ro + 1536 + hoff];
        }
#pragma unroll
        for (int t = 0; t < TT; t++) {
            float s[9];
#pragma unroll
            for (int j = 0; j < 9; j++) {
                float ps = qv[t] * kv[j];
#pragma unroll
                for (int m = 1; m < 64; m <<= 1) ps += __shfl_xor(ps, m, 64);
                s[j] = ps * 0.125f;
            }
            float mx = s[0];
#pragma unroll
            for (int j = 1; j < 9; j++) mx = fmaxf(mx, s[j]);
            float sum = 0.f;
#pragma unroll
            for (int j = 0; j < 9; j++) { s[j] = expf(s[j] - mx); sum += s[j]; }
            float o = 0.f;
#pragma unroll
            for (int j = 0; j < 9; j++) o += s[j] * vv[j];
            o /= sum;
            ctx[(bb + 1 + (u64)t * PP + p) * DM + h * 64 + lane] = (f16)o;
        }
        return;
    }
    __shared__ float sc[CKEY];
    __shared__ float accbuf[4 * 64];
    __shared__ float lbuf[4];
    __shared__ float mxs;
    cls_part_body(qkv, part, blockIdx.x - 4704, sc, accbuf, lbuf, &mxs);
}

// ---------------- phase-B attention: space_attn [0,768) + cls_part [768,3072) ----------------
// Shared-union keeps LDS at the space kernel's 59KB for all blocks; no fences.
__global__ __launch_bounds__(256) void attnB_kernel(const f16* __restrict__ qkv,
                                                    f16* __restrict__ ctx,
                                                    float* __restrict__ part) {
    __shared__ __align__(16) char smem[64 * 232 * 2 + 4 * 16 * 232 * 2];
    int tid = threadIdx.x, lane = tid & 63, wave = tid >> 6;
    if (blockIdx.x >= 768) {
        float* sc     = (float*)smem;
        float* accbuf = (float*)(smem + 512);
        float* lbuf   = (float*)(smem + 1536);
        float* mxs    = (float*)(smem + 1552);
        cls_part_body(qkv, part, blockIdx.x - 768, sc, accbuf, lbuf, mxs);
        return;
    }
    f16* Vt = (f16*)smem;
    f16* Ps = (f16*)(smem + 64 * 232 * 2);
    int g = blockIdx.x;
    int b = g / (NH * TT);
    int rem = g % (NH * TT);
    int h = rem / TT, t = rem % TT;
    u64 bb = (u64)b * SQ;
    int l15 = lane & 15, quad = lane >> 4;

    for (int i = tid; i < 4 * 16 * 232 * 2 / 16; i += 256)
        ((uint4*)Ps)[i] = make_uint4(0u, 0u, 0u, 0u);

    for (int idx = tid; idx < 232 * 8; idx += 256) {
        int c8 = idx / 232;
        int j  = idx - c8 * 232;
        int c  = c8 * 8;
        uint4 vraw = make_uint4(0u, 0u, 0u, 0u);
        if (j < 197) {
            int tok = (j == 0) ? 0 : (1 + t * PP + (j - 1));
            vraw = *(const uint4*)(qkv + (bb + tok) * QKVN + 1536 + h * 64 + c);
        }
        f16x8 vv = *(f16x8*)&vraw;
#pragma unroll
        for (int e = 0; e < 8; e++) Vt[(c + e) * 232 + j] = vv[e];
    }
    __syncthreads();

    f16* myP = Ps + wave * 16 * 232;
    for (int qt = wave; qt < 13; qt += 4) {
        int mloc = qt * 16 + l15;
        int mc = mloc > 195 ? 195 : mloc;
        const f16* qr = qkv + (bb + 1 + (u64)t * PP + mc) * QKVN + h * 64;
        f16x8 qa0 = *(const f16x8*)(qr + quad * 8);
        f16x8 qa1 = *(const f16x8*)(qr + 32 + quad * 8);

        f32x4 s[13];
#pragma unroll
        for (int nt = 0; nt < 13; nt++) { s[nt][0] = 0.f; s[nt][1] = 0.f; s[nt][2] = 0.f; s[nt][3] = 0.f; }
#pragma unroll
        for (int nt = 0; nt < 13; nt++) {
            int n = nt * 16 + l15;
            int ncl = n > 196 ? 196 : n;
            int tok = (ncl == 0) ? 0 : (1 + t * PP + (ncl - 1));
            const f16* kr = qkv + (bb + tok) * QKVN + 768 + h * 64;
            f16x8 kb0 = *(const f16x8*)(kr + quad * 8);
            f16x8 kb1 = *(const f16x8*)(kr + 32 + quad * 8);
            s[nt] = __builtin_amdgcn_mfma_f32_16x16x32_f16(qa0, kb0, s[nt], 0, 0, 0);
            s[nt] = __builtin_amdgcn_mfma_f32_16x16x32_f16(qa1, kb1, s[nt], 0, 0, 0);
        }
        if (l15 >= 5) { s[12][0] = -1e30f; s[12][1] = -1e30f; s[12][2] = -1e30f; s[12][3] = -1e30f; }

        float mx[4] = {-1e30f, -1e30f, -1e30f, -1e30f};
#pragma unroll
        for (int nt = 0; nt < 13; nt++)
#pragma unroll
            for (int r = 0; r < 4; r++) mx[r] = fmaxf(mx[r], s[nt][r]);
#pragma unroll
        for (int m = 1; m < 16; m <<= 1)
#pragma unroll
            for (int r = 0; r < 4; r++) mx[r] = fmaxf(mx[r], __shfl_xor(mx[r], m, 64));

        float sum[4] = {0.f, 0.f, 0.f, 0.f};
#pragma unroll
        for (int nt = 0; nt < 13; nt++)
#pragma unroll
            for (int r = 0; r < 4; r++) {
                float p = exp2f((s[nt][r] - mx[r]) * 0.18033688011112042f);
                s[nt][r] = p;
                sum[r] += p;
            }
#pragma unroll
        for (int m = 1; m < 16; m <<= 1)
#pragma unroll
            for (int r = 0; r < 4; r++) sum[r] += __shfl_xor(sum[r], m, 64);

#pragma unroll
        for (int nt = 0; nt < 13; nt++)
#pragma unroll
            for (int r = 0; r < 4; r++)
                myP[(quad * 4 + r) * 232 + nt * 16 + l15] = (f16)s[nt][r];

        f32x4 o[4];
#pragma unroll
        for (int n2 = 0; n2 < 4; n2++) { o[n2][0] = 0.f; o[n2][1] = 0.f; o[n2][2] = 0.f; o[n2][3] = 0.f; }
#pragma unroll
        for (int kc = 0; kc < 7; kc++) {
            f16x8 pa = *(const f16x8*)(&myP[l15 * 232 + kc * 32 + quad * 8]);
#pragma unroll
            for (int n2 = 0; n2 < 4; n2++) {
                f16x8 vb = *(const f16x8*)(&Vt[(n2 * 16 + l15) * 232 + kc * 32 + quad * 8]);
                o[n2] = __builtin_amdgcn_mfma_f32_16x16x32_f16(pa, vb, o[n2], 0, 0, 0);
            }
        }

        float inv[4];
#pragma unroll
        for (int r = 0; r < 4; r++) inv[r] = 1.f / sum[r];
#pragma unroll
        for (int n2 = 0; n2 < 4; n2++)
#pragma unroll
            for (int r = 0; r < 4; r++) {
                int m = qt * 16 + quad * 4 + r;
                if (m < PP)
                    ctx[(bb + 1 + (u64)t * PP + m) * DM + h * 64 + n2 * 16 + l15] = (f16)(o[n2][r] * inv[r]);
            }
    }
}

// ---------------- host: 13 dispatches, fence-free ----------------
extern "C" void kernel_launch(void* const* d_in, const int* in_sizes, int n_in,
                              void* d_out, int out_size, void* d_ws, size_t ws_size,
                              hipStream_t stream) {
    const float* x_in  = (const float*)d_in[0];
    const float* t_Wq  = (const float*)d_in[1];
    const float* t_bq  = (const float*)d_in[2];
    const float* t_Wk  = (const float*)d_in[3];
    const float* t_bk  = (const float*)d_in[4];
    const float* t_Wv  = (const float*)d_in[5];
    const float* t_bv  = (const float*)d_in[6];
    const float* t_Wo  = (const float*)d_in[7];
    const float* t_bo  = (const float*)d_in[8];
    const float* s_Wq  = (const float*)d_in[9];
    const float* s_bq  = (const float*)d_in[10];
    const float* s_Wk  = (const float*)d_in[11];
    const float* s_bk  = (const float*)d_in[12];
    const float* s_Wv  = (const float*)d_in[13];
    const float* s_bv  = (const float*)d_in[14];
    const float* s_Wo  = (const float*)d_in[15];
    const float* s_bo  = (const float*)d_in[16];
    const float* W1    = (const float*)d_in[17];
    const float* b1    = (const float*)d_in[18];
    const float* W2    = (const float*)d_in[19];
    const float* b2    = (const float*)d_in[20];
    const float* ln1g  = (const float*)d_in[21];
    const float* ln1b  = (const float*)d_in[22];
    const float* ln2g  = (const float*)d_in[23];
    const float* ln2b  = (const float*)d_in[24];
    const float* ln3g  = (const float*)d_in[25];
    const float* ln3b  = (const float*)d_in[26];

    char* ws = (char*)d_ws;
    f16* y    = (f16*)(ws + Y_OFF);
    f16* qkv  = (f16*)(ws + QKV_OFF);
    f16* ctx  = (f16*)(ws + CTX_OFF);
    f16* hbuf = (f16*)(ws + H_OFF);
    float* clsP = (float*)(ws + Y_OFF);   // reuses dead y region (stream-order safe)
    char* wreg = ws + W_OFF;
    f16* tQKV  = (f16*)(wreg);
    f16* tWoT  = (f16*)(wreg + 3538944);
    f16* sQKV  = (f16*)(wreg + 4718592);
    f16* sWoT  = (f16*)(wreg + 8257536);
    f16* W1T   = (f16*)(wreg + 9437184);
    f16* W2T   = (f16*)(wreg + 14155776);
    float* tBias = (float*)(wreg + 18874368);
    float* sBias = (float*)(wreg + 18883584);
    float* xcur  = (float*)d_out;

    dim3 tb(256);
    // 1: weight prep + ln1
    prep_kernel<<<12360, tb, 0, stream>>>(t_Wq, t_Wk, t_Wv, t_Wo, s_Wq, s_Wk, s_Wv, s_Wo,
                                          W1, W2, t_bq, t_bk, t_bv, s_bq, s_bk, s_bv,
                                          x_in, ln1g, ln1b, y,
                                          tQKV, tWoT, sQKV, sWoT, W1T, W2T, tBias, sBias);
    // 2: QKV (time)
    gemm_kernel<QKVN, false, false, true><<<MB_PAD * 18, tb, 0, stream>>>(y, tQKV, tBias, nullptr, nullptr, qkv, 768);
    // 3: time attn + CLS part
    attnA_kernel<<<7008, tb, 0, stream>>>(qkv, ctx, clsP);
    // 4: CLS combine
    cls_comb_kernel<<<24, tb, 0, stream>>>(clsP, ctx);
    // 5: Wo (time) + resid
    gemm_kernel<DM, false, true, false><<<MB_PAD * 6, tb, 0, stream>>>(ctx, tWoT, t_bo, x_in, xcur, nullptr, 768);
    // 6: ln2
    ln_kernel<<<3138, tb, 0, stream>>>(xcur, ln2g, ln2b, y);
    // 7: QKV (space)
    gemm_kernel<QKVN, false, false, true><<<MB_PAD * 18, tb, 0, stream>>>(y, sQKV, sBias, nullptr, nullptr, qkv, 768);
    // 8: space attn + CLS part
    attnB_kernel<<<3072, tb, 0, stream>>>(qkv, ctx, clsP);
    // 9: CLS combine
    cls_comb_kernel<<<24, tb, 0, stream>>>(clsP, ctx);
    // 10: Wo (space) + resid
    gemm_kernel<DM, false, true, false><<<MB_PAD * 6, tb, 0, stream>>>(ctx, sWoT, s_bo, xcur, xcur, nullptr, 768);
    // 11: ln3
    ln_kernel<<<3138, tb, 0, stream>>>(xcur, ln3g, ln3b, y);
    // 12: FFN1 + gelu
    gemm_kernel<D4, true, false, true><<<MB_PAD * 24, tb, 0, stream>>>(y, W1T, b1, nullptr, nullptr, hbuf, 768);
    // 13: FFN2 + resid (final output)
    gemm_kernel<DM, false, true, false><<<MB_PAD * 6, tb, 0, stream>>>(hbuf, W2T, b2, xcur, xcur, nullptr, 3072);
}